// Round 12
// baseline (338.233 us; speedup 1.0000x reference)
//
#include <hip/hip_runtime.h>
#include <hip/hip_bf16.h>
#include <math.h>

#define HIDDEN 1024
#define BATCH 32
#define SEQ 2048
#define MTOT (BATCH * SEQ)   // 65536 rows
#define N_PLANES 8           // 4 n-tiles x 2 wn-waves

#define BM 128
#define BN 256
#define BK 32
#define NKS (HIDDEN / BK)    // 32 K-steps

typedef __attribute__((ext_vector_type(8))) short          bf16x8;
typedef __attribute__((ext_vector_type(8))) unsigned short ushort8;
typedef __attribute__((ext_vector_type(4))) float          f32x4;

#define GLOAD_LDS16(g, l) __builtin_amdgcn_global_load_lds( \
    (const __attribute__((address_space(1))) void*)(g),      \
    (__attribute__((address_space(3))) void*)(l), 16, 0, 0)

#define BARRIER()  asm volatile("s_barrier" ::: "memory")
#define WAITL0()   asm volatile("s_waitcnt lgkmcnt(0)" ::: "memory")
#define WAITV0()   asm volatile("s_waitcnt vmcnt(0)" ::: "memory")
#define WAITV4()   asm volatile("s_waitcnt vmcnt(4)" ::: "memory")
#define WAITV8()   asm volatile("s_waitcnt vmcnt(8)" ::: "memory")
#define WAITV12()  asm volatile("s_waitcnt vmcnt(12)" ::: "memory")
#define SCHED0()   __builtin_amdgcn_sched_barrier(0)

// tanh(x) = 1 - 2/(exp2(x*2*log2e)+1); saturates exactly via exp2 inf/0.
__device__ __forceinline__ float fast_tanh(float x) {
    float e = __builtin_amdgcn_exp2f(x * 2.8853900817779268f);
    return 1.0f - 2.0f * __builtin_amdgcn_rcpf(1.0f + e);
}

// 8x fp32 -> bf16 RNE (bit-trick, same numerics as the convert kernels)
__device__ __forceinline__ ushort8 cvt8(float4 lo, float4 hi) {
    float va[8] = {lo.x, lo.y, lo.z, lo.w, hi.x, hi.y, hi.z, hi.w};
    ushort8 r;
    #pragma unroll
    for (int j = 0; j < 8; ++j) {
        unsigned u = __float_as_uint(va[j]);
        r[j] = (unsigned short)((u + 0x7FFFu + ((u >> 16) & 1u)) >> 16);
    }
    return r;
}

// ---------------------------------------------------------------------------
// fp32 -> bf16 (RNE) conversion for W ONLY (4 MB).
// ---------------------------------------------------------------------------
__global__ __launch_bounds__(256) void convert_w_k(
    const float* __restrict__ W, unsigned short* __restrict__ Wb)
{
    const int i = blockIdx.x * blockDim.x + threadIdx.x;   // 131072 chunks
    float4 a = ((const float4*)W)[(size_t)i * 2];
    float4 b = ((const float4*)W)[(size_t)i * 2 + 1];
    *(ushort8*)&Wb[(size_t)i * 8] = cvt8(a, b);
}

// ---------------------------------------------------------------------------
// MFMA score GEMM, BM=128 x BN=256, BK=32, 4 waves, SINGLE barrier/K-step.
// A NEVER TOUCHES LDS: the 16x16x32 A-frag is k-contiguous per lane
// (lane row = lane&15, k8 = lane>>4), so each lane global-loads its own
// 2xfloat4 per frag (full 64B lines consumed) 1 step ahead and converts
// in-register. Deletes 4 ds_read + 2 ds_write per step and 24KB LDS.
// B: 3-buffer LDS rotation, 2-ahead gload_lds, counted vmcnt.
//
// vmcnt ledger (issue order pinned by SCHED0; vmem = A-loads + gload_lds):
//   entering step t: [A(t)x8, B(t+1)x4]
//   start: WAITV4 -> A(t) retired (B(t+1) may fly). convert af.
//   issue: loadA(t+1)x8, stageB(t+2)x4 -> [B(t+1)4, A(t+1)8, B(t+2)4]
//   end:   WAITV12 -> B(t+1) resident; A(t+1)+B(t+2) stay in flight.
//   tails: t=30 end WAITV8; t=31 start WAITV0, no end wait/barrier.
// Hazard audit (1 barrier): Bs[(t+2)%3] staging at t vs readers at t-1 —
// readers drained by their own WAITL0 before the end-of-(t-1) barrier;
// staging issues after it. Bs[cur] reads at t: staged at t-2, retired by
// end-of-(t-1) WAITV12, published by that barrier. A: registers only.
// PARTIALS=true : wave-private planes partial[(nt*2+(wid&1))*MTOT + m].
// ---------------------------------------------------------------------------
template <bool PARTIALS>
__global__ __launch_bounds__(256, 2) void score_gemm_mfma(
    const float* __restrict__ enc,            // [MTOT][HIDDEN] fp32
    const unsigned short* __restrict__ Wb,    // [HIDDEN][HIDDEN] bf16 (out,in)
    const float* __restrict__ dec,            // [BATCH][HIDDEN]
    const float* __restrict__ v,              // [HIDDEN]
    float* __restrict__ outp)                 // partial[8][MTOT] or scores[MTOT]
{
    __shared__ unsigned short Bs[3][BN][BK];   // 48 KiB

    // XCD-grouping swizzle (bijective: 2048 blocks = 8 xcds x 256 slots)
    const int bid  = blockIdx.x;
    const int xcd  = bid & 7;
    const int slot = bid >> 3;                 // 0..255
    const int mt   = xcd * 64 + (slot >> 2);   // 0..511
    const int nt   = slot & 3;                 // 0..3
    const int m0   = mt * BM;
    const int n0   = nt * BN;

    const int tid  = threadIdx.x;
    const int wid  = tid >> 6;
    const int lane = tid & 63;
    const int wm   = (wid >> 1) * 64;          // 0 / 64
    const int wn   = (wid & 1) * 128;          // 0 / 128

    // B LDS read address (16B slot q = lane>>4 within the 64B k-row)
    const int rowb = (lane & 15) * 64;
    const int swzb = (((lane >> 4) ^ (lane & 3)) * 16);

    // A per-lane direct-load bases: frag fi row = m0+wm+fi*16+(lane&15),
    // k base = (lane>>4)*8 (+ k0 per step).
    const float* encA[4];
    #pragma unroll
    for (int fi = 0; fi < 4; ++fi)
        encA[fi] = enc + (size_t)(m0 + wm + fi * 16 + (lane & 15)) * HIDDEN
                       + (lane >> 4) * 8;

    float4 aA[8];
    auto loadA = [&](int k0) {
        #pragma unroll
        for (int fi = 0; fi < 4; ++fi) {
            aA[2 * fi]     = *(const float4*)(encA[fi] + k0);
            aA[2 * fi + 1] = *(const float4*)(encA[fi] + k0 + 4);
        }
    };

    auto stageB = [&](int buf, int k0) {
        #pragma unroll
        for (int c = 0; c < 4; ++c) {
            const int chw = c * 256 + wid * 64;
            const int ch  = chw + lane;
            const int row = ch >> 2;
            const int gk  = k0 + (((ch & 3) ^ (row & 3)) * 8);
            GLOAD_LDS16(&Wb[(size_t)(n0 + row) * HIDDEN + gk],
                        (char*)&Bs[buf][0][0] + (size_t)chw * 16);
        }
    };

    // prologue: issue B(0), A(0), B(1); retire B(0) only; publish.
    stageB(0, 0);
    loadA(0);
    stageB(1, BK);
    WAITV12(); SCHED0();                      // B(0) resident; A(0)+B(1) fly
    BARRIER();

    f32x4 acc[4][8] = {};
    bf16x8 af[4];

    #pragma unroll 1
    for (int t = 0; t < NKS; ++t) {
        const int cur  = t % 3;
        const int nxt  = (t + 2) % 3;
        const bool more = (t + 2 < NKS);
        const char* Bb = (const char*)&Bs[cur][0][0];

        bf16x8 bf[4];

        // (1) first half of B-frag reads (fj 0-3) — independent of A
        #pragma unroll
        for (int fj = 0; fj < 4; ++fj)
            bf[fj] = *(const bf16x8*)(Bb + (wn + fj * 16) * 64 + rowb + swzb);
        SCHED0();

        // (2) retire A(t); convert to bf16 frags
        if (t + 1 < NKS) { WAITV4(); } else { WAITV0(); }
        SCHED0();
        #pragma unroll
        for (int fi = 0; fi < 4; ++fi)
            af[fi] = __builtin_bit_cast(bf16x8, cvt8(aA[2 * fi], aA[2 * fi + 1]));
        SCHED0();

        // (3) prefetch: A(t+1) regs, B(t+2) LDS (ledger order)
        if (t + 1 < NKS) { loadA((t + 1) * BK); SCHED0(); }
        if (more)        { stageB(nxt, (t + 2) * BK); SCHED0(); }

        // (4) MFMA cluster 1 (fj 0-3)
        WAITL0(); SCHED0();
        __builtin_amdgcn_s_setprio(1);
        #pragma unroll
        for (int fi = 0; fi < 4; ++fi)
            #pragma unroll
            for (int fj = 0; fj < 4; ++fj)
                acc[fi][fj] = __builtin_amdgcn_mfma_f32_16x16x32_bf16(
                    af[fi], bf[fj], acc[fi][fj], 0, 0, 0);
        __builtin_amdgcn_s_setprio(0);
        SCHED0();

        // (5) second half of B reads (fj 4-7, reusing bf regs) + MFMA 2
        #pragma unroll
        for (int fj = 0; fj < 4; ++fj)
            bf[fj] = *(const bf16x8*)(Bb + (wn + (fj + 4) * 16) * 64 + rowb + swzb);
        WAITL0(); SCHED0();
        __builtin_amdgcn_s_setprio(1);
        #pragma unroll
        for (int fi = 0; fi < 4; ++fi)
            #pragma unroll
            for (int fj = 0; fj < 4; ++fj)
                acc[fi][fj + 4] = __builtin_amdgcn_mfma_f32_16x16x32_bf16(
                    af[fi], bf[fj], acc[fi][fj + 4], 0, 0, 0);
        __builtin_amdgcn_s_setprio(0);
        SCHED0();

        // (6) retire B(t+1); publish; next step
        if (more)             { WAITV12(); }
        else if (t + 1 < NKS) { WAITV8(); }
        SCHED0();
        if (t + 1 < NKS) BARRIER();
    }

    // Epilogue. C/D layout: col = lane&15, row = (lane>>4)*4 + reg.
    const int rowgrp = lane >> 4;
    const int col    = lane & 15;
    const int b      = m0 >> 11;               // batch (block-uniform)
    const float* decb = dec + (size_t)b * HIDDEN;

    float2 dv[8];
    #pragma unroll
    for (int fj = 0; fj < 8; ++fj) {
        const int n = n0 + wn + fj * 16 + col;
        dv[fj] = make_float2(decb[n], v[n]);
    }

    const size_t plane = (size_t)(nt * 2 + (wid & 1)) * MTOT;  // wave-private

    #pragma unroll
    for (int fi = 0; fi < 4; ++fi) {
        #pragma unroll
        for (int r = 0; r < 4; ++r) {
            const int m = m0 + wm + fi * 16 + rowgrp * 4 + r;
            float rp = 0.f;
            #pragma unroll
            for (int fj = 0; fj < 8; ++fj)
                rp = fmaf(fast_tanh(acc[fi][fj][r] + dv[fj].x), dv[fj].y, rp);
            rp += __shfl_xor(rp, 1, 64);
            rp += __shfl_xor(rp, 2, 64);
            rp += __shfl_xor(rp, 4, 64);
            rp += __shfl_xor(rp, 8, 64);
            if (col == 0) {
                if (PARTIALS) outp[plane + m] = rp;
                else          atomicAdd(&outp[m], rp);
            }
        }
    }
}

// ---------------------------------------------------------------------------
// softmax over SEQ per batch. PARTIALS: sum 8 partial score planes first.
// ---------------------------------------------------------------------------
template <bool PARTIALS>
__global__ __launch_bounds__(256) void softmax_k(
    const float* __restrict__ scores, float* __restrict__ wts)
{
    __shared__ float redmax[4];
    __shared__ float redsum[4];
    const int b = blockIdx.x;
    const int tid = threadIdx.x;

    float vals[8];
    float lmax = -1e30f;
    #pragma unroll
    for (int j = 0; j < 8; ++j) {
        const int idx = b * SEQ + tid + j * 256;
        float s;
        if (PARTIALS) {
            s = 0.f;
            #pragma unroll
            for (int p = 0; p < N_PLANES; ++p)
                s += scores[(size_t)p * MTOT + idx];
        } else {
            s = scores[idx];
        }
        vals[j] = s;
        lmax = fmaxf(lmax, s);
    }
    #pragma unroll
    for (int off = 1; off < 64; off <<= 1)
        lmax = fmaxf(lmax, __shfl_xor(lmax, off, 64));
    if ((tid & 63) == 0) redmax[tid >> 6] = lmax;
    __syncthreads();
    const float gmax = fmaxf(fmaxf(redmax[0], redmax[1]),
                             fmaxf(redmax[2], redmax[3]));

    float lsum = 0.f;
    #pragma unroll
    for (int j = 0; j < 8; ++j) {
        vals[j] = expf(vals[j] - gmax);
        lsum += vals[j];
    }
    #pragma unroll
    for (int off = 1; off < 64; off <<= 1)
        lsum += __shfl_xor(lsum, off, 64);
    if ((tid & 63) == 0) redsum[tid >> 6] = lsum;
    __syncthreads();
    const float inv = 1.f / (redsum[0] + redsum[1] + redsum[2] + redsum[3]);

    #pragma unroll
    for (int j = 0; j < 8; ++j)
        wts[b * SEQ + tid + j * 256] = vals[j] * inv;
}

// ---------------------------------------------------------------------------
// context[b,h] = sum_s w[b,s] * enc[b,s,h], fp32 enc, float4 loads.
// ---------------------------------------------------------------------------
__global__ __launch_bounds__(256) void context_f32_k(
    const float* __restrict__ enc,
    const float* __restrict__ w,
    float* __restrict__ ctx)
{
    const int b     = blockIdx.x >> 3;
    const int chunk = blockIdx.x & 7;
    const int sOff  = threadIdx.x >> 5;        // 0..7
    const int quad  = threadIdx.x & 31;        // 0..31
    const int h     = chunk * 128 + quad * 4;

    float4 acc = {0.f, 0.f, 0.f, 0.f};
    #pragma unroll 4
    for (int s = sOff; s < SEQ; s += 8) {
        const float ws = w[b * SEQ + s];
        const float4 e = *(const float4*)&enc[(size_t)(b * SEQ + s) * HIDDEN + h];
        acc.x = fmaf(ws, e.x, acc.x);
        acc.y = fmaf(ws, e.y, acc.y);
        acc.z = fmaf(ws, e.z, acc.z);
        acc.w = fmaf(ws, e.w, acc.w);
    }

    __shared__ float4 red[8][32];
    red[sOff][quad] = acc;
    __syncthreads();
    if (sOff == 0) {
        float4 r = red[0][quad];
        #pragma unroll
        for (int t = 1; t < 8; ++t) {
            r.x += red[t][quad].x; r.y += red[t][quad].y;
            r.z += red[t][quad].z; r.w += red[t][quad].w;
        }
        *(float4*)&ctx[b * HIDDEN + h] = r;
    }
}

// ---------------------------------------------------------------------------
// Fallback fp32 path (no workspace beyond scores).
// ---------------------------------------------------------------------------
__global__ __launch_bounds__(256) void score_gemm_f32(
    const float* __restrict__ enc, const float* __restrict__ W,
    const float* __restrict__ dec, const float* __restrict__ v,
    float* __restrict__ scores)
{
    __shared__ float As[16][64 + 1];
    __shared__ float Bs[16][64 + 1];
    const int tid = threadIdx.x;
    const int m0 = (blockIdx.x >> 4) * 64;
    const int n0 = (blockIdx.x & 15) * 64;
    const int ty = tid >> 4, tx = tid & 15;
    const int lr = tid >> 2, lc = tid & 3;
    float acc[4][4] = {};
    for (int k0 = 0; k0 < HIDDEN; k0 += 16) {
        float4 a = *(const float4*)&enc[(size_t)(m0 + lr) * HIDDEN + k0 + lc * 4];
        float4 b = *(const float4*)&W  [(size_t)(n0 + lr) * HIDDEN + k0 + lc * 4];
        __syncthreads();
        As[lc*4+0][lr]=a.x; As[lc*4+1][lr]=a.y; As[lc*4+2][lr]=a.z; As[lc*4+3][lr]=a.w;
        Bs[lc*4+0][lr]=b.x; Bs[lc*4+1][lr]=b.y; Bs[lc*4+2][lr]=b.z; Bs[lc*4+3][lr]=b.w;
        __syncthreads();
        #pragma unroll
        for (int k = 0; k < 16; ++k) {
            float4 av = *(const float4*)&As[k][ty * 4];
            float4 bv = *(const float4*)&Bs[k][tx * 4];
            float aa[4] = {av.x, av.y, av.z, av.w};
            float bb[4] = {bv.x, bv.y, bv.z, bv.w};
            #pragma unroll
            for (int i = 0; i < 4; ++i)
                #pragma unroll
                for (int j = 0; j < 4; ++j)
                    acc[i][j] = fmaf(aa[i], bb[j], acc[i][j]);
        }
    }
    float rowpart[4];
    #pragma unroll
    for (int i = 0; i < 4; ++i) {
        const int m = m0 + ty * 4 + i;
        const int b = m >> 11;
        float rp = 0.f;
        #pragma unroll
        for (int j = 0; j < 4; ++j) {
            const int n = n0 + tx * 4 + j;
            rp = fmaf(fast_tanh(acc[i][j] + dec[b * HIDDEN + n]), v[n], rp);
        }
        rowpart[i] = rp;
    }
    #pragma unroll
    for (int off = 1; off <= 8; off <<= 1)
        #pragma unroll
        for (int i = 0; i < 4; ++i)
            rowpart[i] += __shfl_xor(rowpart[i], off, 64);
    if (tx == 0)
        #pragma unroll
        for (int i = 0; i < 4; ++i)
            atomicAdd(&scores[m0 + ty * 4 + i], rowpart[i]);
}

// ---------------------------------------------------------------------------
extern "C" void kernel_launch(void* const* d_in, const int* in_sizes, int n_in,
                              void* d_out, int out_size, void* d_ws, size_t ws_size,
                              hipStream_t stream) {
    const float* dec = (const float*)d_in[0];   // [32, 1024]
    const float* enc = (const float*)d_in[1];   // [32, 2048, 1024]
    const float* W   = (const float*)d_in[2];   // [1024, 1024]
    const float* v   = (const float*)d_in[3];   // [1, 1024]

    float* out = (float*)d_out;
    float* ctx = out;                           // [32, 1024]
    float* wts = out + BATCH * HIDDEN;          // [32, 2048]

    const size_t part_bytes   = (size_t)N_PLANES * MTOT * sizeof(float); // 2 MiB
    const size_t wb_bytes     = (size_t)HIDDEN * HIDDEN * 2;             // 2 MiB
    const size_t scores_bytes = (size_t)MTOT * sizeof(float);            // 256 KiB
    const size_t need = part_bytes + wb_bytes;                           // 4 MiB

    if (ws_size >= need) {
        float* partial       = (float*)d_ws;
        unsigned short* Wb   = (unsigned short*)((char*)d_ws + part_bytes);

        convert_w_k<<<dim3(512), dim3(256), 0, stream>>>(W, Wb);
        score_gemm_mfma<true><<<dim3(2048), dim3(256), 0, stream>>>(enc, Wb, dec, v, partial);
        softmax_k<true><<<dim3(BATCH), dim3(256), 0, stream>>>(partial, wts);
        context_f32_k<<<dim3(BATCH * 8), dim3(256), 0, stream>>>(enc, wts, ctx);
    } else {
        float* scores = (float*)d_ws;
        (void)hipMemsetAsync(scores, 0, scores_bytes, stream);
        score_gemm_f32<<<dim3(16384), dim3(256), 0, stream>>>(enc, W, dec, v, scores);
        softmax_k<false><<<dim3(BATCH), dim3(256), 0, stream>>>(scores, wts);
        context_f32_k<<<dim3(BATCH * 8), dim3(256), 0, stream>>>(enc, wts, ctx);
    }
}

// Round 13
// 295.898 us; speedup vs baseline: 1.1431x; 1.1431x over previous
//
#include <hip/hip_runtime.h>
#include <hip/hip_bf16.h>
#include <math.h>

#define HIDDEN 1024
#define BATCH 32
#define SEQ 2048
#define MTOT (BATCH * SEQ)   // 65536 rows
#define N_PLANES 8           // 4 n-tiles x 2 wn-waves

#define BM 128
#define BN 256
#define BK 32
#define NKS (HIDDEN / BK)    // 32 K-steps

typedef __attribute__((ext_vector_type(8))) short          bf16x8;
typedef __attribute__((ext_vector_type(8))) unsigned short ushort8;
typedef __attribute__((ext_vector_type(4))) float          f32x4;

#define GLOAD_LDS16(g, l) __builtin_amdgcn_global_load_lds( \
    (const __attribute__((address_space(1))) void*)(g),      \
    (__attribute__((address_space(3))) void*)(l), 16, 0, 0)

#define BARRIER() asm volatile("s_barrier" ::: "memory")
#define WAITL0()  asm volatile("s_waitcnt lgkmcnt(0)" ::: "memory")
#define WAITL6()  asm volatile("s_waitcnt lgkmcnt(6)" ::: "memory")
#define WAITV4()  asm volatile("s_waitcnt vmcnt(4)" ::: "memory")
#define WAITV8()  asm volatile("s_waitcnt vmcnt(8)" ::: "memory")
#define WAITV12() asm volatile("s_waitcnt vmcnt(12)" ::: "memory")
#define WAITV0()  asm volatile("s_waitcnt vmcnt(0)" ::: "memory")
#define SCHED0()  __builtin_amdgcn_sched_barrier(0)

// tanh(x) = 1 - 2/(exp2(x*2*log2e)+1); saturates exactly via exp2 inf/0.
__device__ __forceinline__ float fast_tanh(float x) {
    float e = __builtin_amdgcn_exp2f(x * 2.8853900817779268f);
    return 1.0f - 2.0f * __builtin_amdgcn_rcpf(1.0f + e);
}

// 8x fp32 -> bf16 RNE (bit-trick, same numerics as the convert kernels)
__device__ __forceinline__ ushort8 cvt8(float4 lo, float4 hi) {
    float va[8] = {lo.x, lo.y, lo.z, lo.w, hi.x, hi.y, hi.z, hi.w};
    ushort8 r;
    #pragma unroll
    for (int j = 0; j < 8; ++j) {
        unsigned u = __float_as_uint(va[j]);
        r[j] = (unsigned short)((u + 0x7FFFu + ((u >> 16) & 1u)) >> 16);
    }
    return r;
}

// ---------------------------------------------------------------------------
// fp32 -> bf16 (RNE) conversion for W ONLY (4 MB).
// ---------------------------------------------------------------------------
__global__ __launch_bounds__(256) void convert_w_k(
    const float* __restrict__ W, unsigned short* __restrict__ Wb)
{
    const int i = blockIdx.x * blockDim.x + threadIdx.x;   // 131072 chunks
    float4 a = ((const float4*)W)[(size_t)i * 2];
    float4 b = ((const float4*)W)[(size_t)i * 2 + 1];
    *(ushort8*)&Wb[(size_t)i * 8] = cvt8(a, b);
}

// ---------------------------------------------------------------------------
// MFMA score GEMM (round-10 structure): BM=128 x BN=256, BK=32, 4 waves,
// 3-buffer rotation, fused A-conversion (1-step-deferred write), SINGLE
// barrier per K-step, counted vmcnt.  NEW (WRITEB): the nt==0 block of each
// m-tile also stores its converted A ushort8s to encb (global) so the
// context kernel can read bf16 — the conversion is free, the store rides
// the GEMM's idle HBM write BW.
//
// vmcnt ledger (issue order pinned by SCHED0; stores enter the queue inside
// writeA, BEFORE the next loadA/stageB, so they are always OLDER than the
// loads each wait targets — WAITV4/WAITV12 counts are unchanged):
//   entering t: [B(t+1)x4(residual), st x2?]... steady state after end-wait:
//   [A(t+1)x8, B(t+1)x4]. WAITV4 -> A(t+1) done -> writeA(+2 st).
//   issue A(t+2)x8 + B(t+2)x4. end WAITV12 -> retires B(t+1)+st;
//   leaves A(t+2)+B(t+2). Tails: t=30 WAITV0; t=31 none.
// Hazard audit (1 barrier) unchanged from round 10 (see comments there).
// ---------------------------------------------------------------------------
template <bool WRITEB>
__global__ __launch_bounds__(256, 2) void score_gemm_mfma(
    const float* __restrict__ enc,            // [MTOT][HIDDEN] fp32
    const unsigned short* __restrict__ Wb,    // [HIDDEN][HIDDEN] bf16 (out,in)
    const float* __restrict__ dec,            // [BATCH][HIDDEN]
    const float* __restrict__ v,              // [HIDDEN]
    float* __restrict__ outp,                 // partial[8][MTOT]
    unsigned short* __restrict__ encb)        // [MTOT][HIDDEN] bf16 out (WRITEB)
{
    __shared__ unsigned short As[3][BM][BK];   // 24 KiB
    __shared__ unsigned short Bs[3][BN][BK];   // 48 KiB

    // XCD-grouping swizzle (bijective: 2048 blocks = 8 xcds x 256 slots)
    const int bid  = blockIdx.x;
    const int xcd  = bid & 7;
    const int slot = bid >> 3;                 // 0..255
    const int mt   = xcd * 64 + (slot >> 2);   // 0..511
    const int nt   = slot & 3;                 // 0..3
    const int m0   = mt * BM;
    const int n0   = nt * BN;

    const int tid  = threadIdx.x;
    const int wid  = tid >> 6;
    const int lane = tid & 63;
    const int wm   = (wid >> 1) * 64;          // 0 / 64
    const int wn   = (wid & 1) * 128;          // 0 / 128

    // LDS read address (16B slot within the 64B k-row)
    const int rowb = (lane & 15) * 64;
    const int swzb = (((lane >> 4) ^ (lane & 3)) * 16);

    // A chunks (2 per thread); global k pre-swizzled to keep LDS linear
    const int chA0  = wid * 64 + lane;
    const int chA1  = 256 + wid * 64 + lane;
    const int rowA0 = chA0 >> 2, rowA1 = chA1 >> 2;
    const int swA0  = ((chA0 & 3) ^ (rowA0 & 3)) * 8;
    const int swA1  = ((chA1 & 3) ^ (rowA1 & 3)) * 8;
    const float* encA0 = &enc[(size_t)(m0 + rowA0) * HIDDEN + swA0];
    const float* encA1 = &enc[(size_t)(m0 + rowA1) * HIDDEN + swA1];
    unsigned short* encbA0 =
        WRITEB ? &encb[(size_t)(m0 + rowA0) * HIDDEN + swA0] : nullptr;
    unsigned short* encbA1 =
        WRITEB ? &encb[(size_t)(m0 + rowA1) * HIDDEN + swA1] : nullptr;

    auto loadA = [&](int k0, float4& l0, float4& h0, float4& l1, float4& h1) {
        l0 = *(const float4*)(encA0 + k0);
        h0 = *(const float4*)(encA0 + k0 + 4);
        l1 = *(const float4*)(encA1 + k0);
        h1 = *(const float4*)(encA1 + k0 + 4);
    };
    // writeA: LDS write (+ optional global bf16 side-write, nt==0 only).
    // Stores are issued BEFORE the caller's next loadA/stageB (ledger).
    auto writeA = [&](int buf, int k0,
                      float4 l0, float4 h0, float4 l1, float4 h1) {
        ushort8 r0 = cvt8(l0, h0);
        ushort8 r1 = cvt8(l1, h1);
        *(ushort8*)((char*)&As[buf][0][0] + (size_t)chA0 * 16) = r0;
        *(ushort8*)((char*)&As[buf][0][0] + (size_t)chA1 * 16) = r1;
        if constexpr (WRITEB) {
            if (nt == 0) {
                *(ushort8*)(encbA0 + k0) = r0;
                *(ushort8*)(encbA1 + k0) = r1;
            }
        }
    };
    auto stageB = [&](int buf, int k0) {
        #pragma unroll
        for (int c = 0; c < 4; ++c) {
            const int chw = c * 256 + wid * 64;
            const int ch  = chw + lane;
            const int row = ch >> 2;
            const int gk  = k0 + (((ch & 3) ^ (row & 3)) * 8);
            GLOAD_LDS16(&Wb[(size_t)(n0 + row) * HIDDEN + gk],
                        (char*)&Bs[buf][0][0] + (size_t)chw * 16);
        }
    };

    // prologue: write As[0], As[1]; stage B(0), B(1); leave B(1) in flight.
    {
        float4 p0l0, p0h0, p0l1, p0h1, p1l0, p1h0, p1l1, p1h1;
        loadA(0, p0l0, p0h0, p0l1, p0h1);
        stageB(0, 0);
        loadA(BK, p1l0, p1h0, p1l1, p1h1);
        stageB(1, BK);
        WAITV12(); SCHED0();                     // A(0)+B(0) done
        writeA(0, 0, p0l0, p0h0, p0l1, p0h1);
        WAITV4(); SCHED0();                      // A(1) done
        writeA(1, BK, p1l0, p1h0, p1l1, p1h1);
        WAITL0(); SCHED0();
        BARRIER();
    }

    f32x4 acc[4][8] = {};
    float4 al0, ah0, al1, ah1;   // A(t+2) fp32 in flight (one set)

    #pragma unroll 1
    for (int t = 0; t < NKS; ++t) {
        const int cur  = t % 3;
        const int nxt  = (t + 2) % 3;
        const int prv  = (t + 1) % 3;           // buffer receiving A(t+1)
        const bool more = (t + 2 < NKS);
        const int knxt = (t + 2) * BK;
        const char* Ab = (const char*)&As[cur][0][0];
        const char* Bb = (const char*)&Bs[cur][0][0];

        bf16x8 af[4], bf[8];

        // issue all 12 ds_reads of buf cur (af0-3, bf0-7 in order)
        #pragma unroll
        for (int fi = 0; fi < 4; ++fi)
            af[fi] = *(const bf16x8*)(Ab + (wm + fi * 16) * 64 + rowb + swzb);
        #pragma unroll
        for (int fj = 0; fj < 8; ++fj)
            bf[fj] = *(const bf16x8*)(Bb + (wn + fj * 16) * 64 + rowb + swzb);
        SCHED0();

        // retire A(t+1) fp32 loads; convert + ds_write (+encb store) into prv
        if (t >= 1 && t + 1 < NKS) {
            WAITV4(); SCHED0();
            writeA(prv, (t + 1) * BK, al0, ah0, al1, ah1);
            SCHED0();
        }
        // issue next prefetch (A then B — ledger order)
        if (more) {
            loadA(knxt, al0, ah0, al1, ah1);
            SCHED0();
            stageB(nxt, knxt);
            SCHED0();
        }

        // MFMA cluster 1: needs af0-3 + bf0-3 (first 8 ds_reads)
        WAITL6(); SCHED0();
        __builtin_amdgcn_s_setprio(1);
        #pragma unroll
        for (int fi = 0; fi < 4; ++fi)
            #pragma unroll
            for (int fj = 0; fj < 4; ++fj)
                acc[fi][fj] = __builtin_amdgcn_mfma_f32_16x16x32_bf16(
                    af[fi], bf[fj], acc[fi][fj], 0, 0, 0);
        __builtin_amdgcn_s_setprio(0);
        SCHED0();

        // MFMA cluster 2: needs bf4-7 (drains everything incl. writeA)
        WAITL0(); SCHED0();
        __builtin_amdgcn_s_setprio(1);
        #pragma unroll
        for (int fi = 0; fi < 4; ++fi)
            #pragma unroll
            for (int fj = 4; fj < 8; ++fj)
                acc[fi][fj] = __builtin_amdgcn_mfma_f32_16x16x32_bf16(
                    af[fi], bf[fj], acc[fi][fj], 0, 0, 0);
        __builtin_amdgcn_s_setprio(0);
        SCHED0();

        // retire B(t+1) (+stores); publish; next step
        if (more)             { WAITV12(); }
        else if (t + 1 < NKS) { WAITV0(); }     // t=30: drain B(31)+stores
        SCHED0();
        if (t + 1 < NKS) BARRIER();
    }

    // Epilogue. C/D layout: col = lane&15, row = (lane>>4)*4 + reg.
    const int rowgrp = lane >> 4;
    const int col    = lane & 15;
    const int b      = m0 >> 11;               // batch (block-uniform)
    const float* decb = dec + (size_t)b * HIDDEN;

    float2 dv[8];
    #pragma unroll
    for (int fj = 0; fj < 8; ++fj) {
        const int n = n0 + wn + fj * 16 + col;
        dv[fj] = make_float2(decb[n], v[n]);
    }

    const size_t plane = (size_t)(nt * 2 + (wid & 1)) * MTOT;  // wave-private

    #pragma unroll
    for (int fi = 0; fi < 4; ++fi) {
        #pragma unroll
        for (int r = 0; r < 4; ++r) {
            const int m = m0 + wm + fi * 16 + rowgrp * 4 + r;
            float rp = 0.f;
            #pragma unroll
            for (int fj = 0; fj < 8; ++fj)
                rp = fmaf(fast_tanh(acc[fi][fj][r] + dv[fj].x), dv[fj].y, rp);
            rp += __shfl_xor(rp, 1, 64);
            rp += __shfl_xor(rp, 2, 64);
            rp += __shfl_xor(rp, 4, 64);
            rp += __shfl_xor(rp, 8, 64);
            if (col == 0) outp[plane + m] = rp;
        }
    }
}

// ---------------------------------------------------------------------------
// softmax over SEQ per batch. PARTIALS: sum 8 partial score planes first.
// ---------------------------------------------------------------------------
template <bool PARTIALS>
__global__ __launch_bounds__(256) void softmax_k(
    const float* __restrict__ scores, float* __restrict__ wts)
{
    __shared__ float redmax[4];
    __shared__ float redsum[4];
    const int b = blockIdx.x;
    const int tid = threadIdx.x;

    float vals[8];
    float lmax = -1e30f;
    #pragma unroll
    for (int j = 0; j < 8; ++j) {
        const int idx = b * SEQ + tid + j * 256;
        float s;
        if (PARTIALS) {
            s = 0.f;
            #pragma unroll
            for (int p = 0; p < N_PLANES; ++p)
                s += scores[(size_t)p * MTOT + idx];
        } else {
            s = scores[idx];
        }
        vals[j] = s;
        lmax = fmaxf(lmax, s);
    }
    #pragma unroll
    for (int off = 1; off < 64; off <<= 1)
        lmax = fmaxf(lmax, __shfl_xor(lmax, off, 64));
    if ((tid & 63) == 0) redmax[tid >> 6] = lmax;
    __syncthreads();
    const float gmax = fmaxf(fmaxf(redmax[0], redmax[1]),
                             fmaxf(redmax[2], redmax[3]));

    float lsum = 0.f;
    #pragma unroll
    for (int j = 0; j < 8; ++j) {
        vals[j] = expf(vals[j] - gmax);
        lsum += vals[j];
    }
    #pragma unroll
    for (int off = 1; off < 64; off <<= 1)
        lsum += __shfl_xor(lsum, off, 64);
    if ((tid & 63) == 0) redsum[tid >> 6] = lsum;
    __syncthreads();
    const float inv = 1.f / (redsum[0] + redsum[1] + redsum[2] + redsum[3]);

    #pragma unroll
    for (int j = 0; j < 8; ++j)
        wts[b * SEQ + tid + j * 256] = vals[j] * inv;
}

// ---------------------------------------------------------------------------
// context[b,h] = sum_s w[b,s] * enc[b,s,h], reading the bf16 enc copy
// produced by the GEMM's side-write (halves context HBM traffic).
// ---------------------------------------------------------------------------
__global__ __launch_bounds__(256) void context_bf16_k(
    const unsigned short* __restrict__ encb,
    const float* __restrict__ w,
    float* __restrict__ ctx)
{
    const int b     = blockIdx.x >> 3;
    const int chunk = blockIdx.x & 7;
    const int sOff  = threadIdx.x >> 4;
    const int hg    = threadIdx.x & 15;
    const int h     = chunk * 128 + hg * 8;

    float acc[8] = {};
    for (int s = sOff; s < SEQ; s += 16) {
        const float ws = w[b * SEQ + s];
        ushort8 e = *(const ushort8*)&encb[(size_t)(b * SEQ + s) * HIDDEN + h];
        #pragma unroll
        for (int j = 0; j < 8; ++j)
            acc[j] = fmaf(ws, __uint_as_float((unsigned)e[j] << 16), acc[j]);
    }
    __shared__ float red[16][128];
    #pragma unroll
    for (int j = 0; j < 8; ++j) red[sOff][hg * 8 + j] = acc[j];
    __syncthreads();
    if (threadIdx.x < 128) {
        float r = 0.f;
        #pragma unroll
        for (int g = 0; g < 16; ++g) r += red[g][threadIdx.x];
        ctx[b * HIDDEN + chunk * 128 + threadIdx.x] = r;
    }
}

// ---------------------------------------------------------------------------
// context fallback: fp32 enc, float4 loads.
// ---------------------------------------------------------------------------
__global__ __launch_bounds__(256) void context_f32_k(
    const float* __restrict__ enc,
    const float* __restrict__ w,
    float* __restrict__ ctx)
{
    const int b     = blockIdx.x >> 3;
    const int chunk = blockIdx.x & 7;
    const int sOff  = threadIdx.x >> 5;        // 0..7
    const int quad  = threadIdx.x & 31;        // 0..31
    const int h     = chunk * 128 + quad * 4;

    float4 acc = {0.f, 0.f, 0.f, 0.f};
    #pragma unroll 4
    for (int s = sOff; s < SEQ; s += 8) {
        const float ws = w[b * SEQ + s];
        const float4 e = *(const float4*)&enc[(size_t)(b * SEQ + s) * HIDDEN + h];
        acc.x = fmaf(ws, e.x, acc.x);
        acc.y = fmaf(ws, e.y, acc.y);
        acc.z = fmaf(ws, e.z, acc.z);
        acc.w = fmaf(ws, e.w, acc.w);
    }

    __shared__ float4 red[8][32];
    red[sOff][quad] = acc;
    __syncthreads();
    if (sOff == 0) {
        float4 r = red[0][quad];
        #pragma unroll
        for (int t = 1; t < 8; ++t) {
            r.x += red[t][quad].x; r.y += red[t][quad].y;
            r.z += red[t][quad].z; r.w += red[t][quad].w;
        }
        *(float4*)&ctx[b * HIDDEN + h] = r;
    }
}

// ---------------------------------------------------------------------------
// Fallback fp32 path (no workspace beyond scores).
// ---------------------------------------------------------------------------
__global__ __launch_bounds__(256) void score_gemm_f32(
    const float* __restrict__ enc, const float* __restrict__ W,
    const float* __restrict__ dec, const float* __restrict__ v,
    float* __restrict__ scores)
{
    __shared__ float As[16][64 + 1];
    __shared__ float Bs[16][64 + 1];
    const int tid = threadIdx.x;
    const int m0 = (blockIdx.x >> 4) * 64;
    const int n0 = (blockIdx.x & 15) * 64;
    const int ty = tid >> 4, tx = tid & 15;
    const int lr = tid >> 2, lc = tid & 3;
    float acc[4][4] = {};
    for (int k0 = 0; k0 < HIDDEN; k0 += 16) {
        float4 a = *(const float4*)&enc[(size_t)(m0 + lr) * HIDDEN + k0 + lc * 4];
        float4 b = *(const float4*)&W  [(size_t)(n0 + lr) * HIDDEN + k0 + lc * 4];
        __syncthreads();
        As[lc*4+0][lr]=a.x; As[lc*4+1][lr]=a.y; As[lc*4+2][lr]=a.z; As[lc*4+3][lr]=a.w;
        Bs[lc*4+0][lr]=b.x; Bs[lc*4+1][lr]=b.y; Bs[lc*4+2][lr]=b.z; Bs[lc*4+3][lr]=b.w;
        __syncthreads();
        #pragma unroll
        for (int k = 0; k < 16; ++k) {
            float4 av = *(const float4*)&As[k][ty * 4];
            float4 bv = *(const float4*)&Bs[k][tx * 4];
            float aa[4] = {av.x, av.y, av.z, av.w};
            float bb[4] = {bv.x, bv.y, bv.z, bv.w};
            #pragma unroll
            for (int i = 0; i < 4; ++i)
                #pragma unroll
                for (int j = 0; j < 4; ++j)
                    acc[i][j] = fmaf(aa[i], bb[j], acc[i][j]);
        }
    }
    float rowpart[4];
    #pragma unroll
    for (int i = 0; i < 4; ++i) {
        const int m = m0 + ty * 4 + i;
        const int b = m >> 11;
        float rp = 0.f;
        #pragma unroll
        for (int j = 0; j < 4; ++j) {
            const int n = n0 + tx * 4 + j;
            rp = fmaf(fast_tanh(acc[i][j] + dec[b * HIDDEN + n]), v[n], rp);
        }
        rowpart[i] = rp;
    }
    #pragma unroll
    for (int off = 1; off <= 8; off <<= 1)
        #pragma unroll
        for (int i = 0; i < 4; ++i)
            rowpart[i] += __shfl_xor(rowpart[i], off, 64);
    if (tx == 0)
        #pragma unroll
        for (int i = 0; i < 4; ++i)
            atomicAdd(&scores[m0 + ty * 4 + i], rowpart[i]);
}

// ---------------------------------------------------------------------------
extern "C" void kernel_launch(void* const* d_in, const int* in_sizes, int n_in,
                              void* d_out, int out_size, void* d_ws, size_t ws_size,
                              hipStream_t stream) {
    const float* dec = (const float*)d_in[0];   // [32, 1024]
    const float* enc = (const float*)d_in[1];   // [32, 2048, 1024]
    const float* W   = (const float*)d_in[2];   // [1024, 1024]
    const float* v   = (const float*)d_in[3];   // [1, 1024]

    float* out = (float*)d_out;
    float* ctx = out;                           // [32, 1024]
    float* wts = out + BATCH * HIDDEN;          // [32, 2048]

    const size_t part_bytes   = (size_t)N_PLANES * MTOT * sizeof(float); // 2 MiB
    const size_t wb_bytes     = (size_t)HIDDEN * HIDDEN * 2;             // 2 MiB
    const size_t encb_bytes   = (size_t)MTOT * HIDDEN * 2;               // 128 MiB
    const size_t scores_bytes = (size_t)MTOT * sizeof(float);            // 256 KiB

    const size_t need_full = part_bytes + wb_bytes + encb_bytes;         // 132 MiB
    const size_t need_mid  = part_bytes + wb_bytes;                      // 4 MiB

    if (ws_size >= need_full) {
        float* partial     = (float*)d_ws;
        unsigned short* Wb = (unsigned short*)((char*)d_ws + part_bytes);
        unsigned short* encb =
            (unsigned short*)((char*)d_ws + part_bytes + wb_bytes);

        convert_w_k<<<dim3(512), dim3(256), 0, stream>>>(W, Wb);
        score_gemm_mfma<true><<<dim3(2048), dim3(256), 0, stream>>>(
            enc, Wb, dec, v, partial, encb);
        softmax_k<true><<<dim3(BATCH), dim3(256), 0, stream>>>(partial, wts);
        context_bf16_k<<<dim3(BATCH * 8), dim3(256), 0, stream>>>(encb, wts, ctx);
    } else if (ws_size >= need_mid) {
        float* partial     = (float*)d_ws;
        unsigned short* Wb = (unsigned short*)((char*)d_ws + part_bytes);

        convert_w_k<<<dim3(512), dim3(256), 0, stream>>>(W, Wb);
        score_gemm_mfma<false><<<dim3(2048), dim3(256), 0, stream>>>(
            enc, Wb, dec, v, partial, nullptr);
        softmax_k<true><<<dim3(BATCH), dim3(256), 0, stream>>>(partial, wts);
        context_f32_k<<<dim3(BATCH * 8), dim3(256), 0, stream>>>(enc, wts, ctx);
    } else {
        float* scores = (float*)d_ws;
        (void)hipMemsetAsync(scores, 0, scores_bytes, stream);
        score_gemm_f32<<<dim3(16384), dim3(256), 0, stream>>>(enc, W, dec, v, scores);
        softmax_k<false><<<dim3(BATCH), dim3(256), 0, stream>>>(scores, wts);
        context_f32_k<<<dim3(BATCH * 8), dim3(256), 0, stream>>>(enc, wts, ctx);
    }
}

// Round 15
// 268.333 us; speedup vs baseline: 1.2605x; 1.1027x over previous
//
#include <hip/hip_runtime.h>
#include <hip/hip_bf16.h>
#include <math.h>

#define HIDDEN 1024
#define BATCH 32
#define SEQ 2048
#define MTOT (BATCH * SEQ)   // 65536 rows
#define N_PLANES 16          // 4 nt-tiles x 4 waveN columns

#define QBM 256
#define QBN 256
#define QBK 64
#define NTILE (HIDDEN / QBK) // 16 K-tiles
#define NITER (NTILE / 2)    // 8 iterations (2 K-tiles each)

typedef __attribute__((ext_vector_type(8))) short          bf16x8;
typedef __attribute__((ext_vector_type(8))) unsigned short ushort8;
typedef __attribute__((ext_vector_type(4))) float          f32x4;

#define GLOAD_LDS16(g, l) __builtin_amdgcn_global_load_lds( \
    (const __attribute__((address_space(1))) void*)(g),      \
    (__attribute__((address_space(3))) void*)(l), 16, 0, 0)

#define BARRIER() asm volatile("s_barrier" ::: "memory")
#define WAITV4()  asm volatile("s_waitcnt vmcnt(4)" ::: "memory")
#define WAITV0()  asm volatile("s_waitcnt vmcnt(0)" ::: "memory")
#define SCHED0()  __builtin_amdgcn_sched_barrier(0)

// tanh(x) = 1 - 2/(exp2(x*2*log2e)+1); saturates exactly via exp2 inf/0.
__device__ __forceinline__ float fast_tanh(float x) {
    float e = __builtin_amdgcn_exp2f(x * 2.8853900817779268f);
    return 1.0f - 2.0f * __builtin_amdgcn_rcpf(1.0f + e);
}

// 8x fp32 -> bf16 RNE
__device__ __forceinline__ ushort8 cvt8(float4 lo, float4 hi) {
    float va[8] = {lo.x, lo.y, lo.z, lo.w, hi.x, hi.y, hi.z, hi.w};
    ushort8 r;
    #pragma unroll
    for (int j = 0; j < 8; ++j) {
        unsigned u = __float_as_uint(va[j]);
        r[j] = (unsigned short)((u + 0x7FFFu + ((u >> 16) & 1u)) >> 16);
    }
    return r;
}

// ---------------------------------------------------------------------------
// fp32 -> bf16 (RNE) conversion for enc AND W in one launch (round-2 proven).
// ---------------------------------------------------------------------------
__global__ __launch_bounds__(256) void convert_k(
    const float* __restrict__ enc, unsigned short* __restrict__ encb,
    const float* __restrict__ W,   unsigned short* __restrict__ Wb)
{
    const int n8_enc = MTOT * (HIDDEN / 8);
    const int n8_tot = n8_enc + HIDDEN * (HIDDEN / 8);
    for (int i = blockIdx.x * blockDim.x + threadIdx.x; i < n8_tot;
         i += gridDim.x * blockDim.x) {
        const float* src; unsigned short* dst; size_t idx;
        if (i < n8_enc) { src = enc; dst = encb; idx = (size_t)i; }
        else            { src = W;   dst = Wb;   idx = (size_t)(i - n8_enc); }
        float4 a = ((const float4*)src)[idx * 2];
        float4 b = ((const float4*)src)[idx * 2 + 1];
        *(ushort8*)&dst[idx * 8] = cvt8(a, b);
    }
}

// ---------------------------------------------------------------------------
// 8-phase 256x256 MFMA score GEMM (m201 template port), RACE-FIXED schedule.
//
// Region read/stage discipline (the round-14 bug was staging regions still
// being read this iteration):
//   A d0 halves: read P1+P3  -> staged P5 (h0), P6 (h1)   [tile 2i+2]
//   B d0 halves: read P1+P2  -> staged P3 (h0), P4 (h1)   [tile 2i+2]
//   A d1 halves: read P5+P7  -> staged NEXT-iter P1 (h0), P2 (h1) [tile 2i+1]
//   B d1 halves: read P5+P6  -> staged P7 (h0), P8 (h1)   [tile 2i+3]
// Every restage is >= 2 barriers after the region's last read (readers'
// own lgkm drains before their closing barrier).
//
// vmcnt ledger (2 gloads per ST; issue order P1..P8):
//   steady-state at P4: outstanding = prevP7,prevP8,P1..P4 = 12.
//     WAITV4 retires 8 = prev B-d1 (read P5/P6) + cur A-d1 (read P5/P7). OK
//   steady-state at P8: outstanding = P3..P8 = 12.
//     WAITV4 retires 8 = P3..P6 = d0 A+B (read next P1..P3). Keeps P7,P8.
//   prologue: stage d0 full + B-d1 (12), WAITV4 retires d0 (8).
//   tails: last iter P4 -> WAITV0 (8 outstanding); P8 -> nothing.
// ---------------------------------------------------------------------------
__global__ __launch_bounds__(512, 2) void gemm8p(
    const unsigned short* __restrict__ encb,  // [MTOT][HIDDEN] bf16
    const unsigned short* __restrict__ Wb,    // [HIDDEN][HIDDEN] bf16 (out,in)
    const float* __restrict__ dec,            // [BATCH][HIDDEN]
    const float* __restrict__ v,              // [HIDDEN]
    float* __restrict__ outp)                 // partial[16][MTOT]
{
    __shared__ unsigned short LA[2][QBM][QBK];   // 64 KB
    __shared__ unsigned short LB[2][QBN][QBK];   // 64 KB

    // XCD swizzle: 1024 blocks = 8 xcds x 128 slots; nt fastest per m-tile.
    const int bid  = blockIdx.x;
    const int xcd  = bid & 7;
    const int slot = bid >> 3;                // 0..127
    const int mt   = xcd * 32 + (slot >> 2);  // 0..255
    const int nt   = slot & 3;                // 0..3
    const int m0   = mt * QBM;
    const int n0   = nt * QBN;

    const int tid   = threadIdx.x;
    const int wid   = tid >> 6;
    const int lane  = tid & 63;
    const int waveM = (wid >> 2) * 128;       // 0 / 128
    const int waveN = (wid & 3) * 64;         // 0..192
    const int lr    = lane & 15;
    const int lq    = lane >> 4;

#define RD_A(d, qm) do { _Pragma("unroll") for (int fi = 0; fi < 4; ++fi) { \
        const int rr = waveM + (qm) * 64 + fi * 16 + lr;                    \
        const int kx = ((rr >> 2) & 1) << 4;                                \
        _Pragma("unroll") for (int ks = 0; ks < 2; ++ks)                    \
            af[fi][ks] = *(const bf16x8*)&LA[d][rr][(ks * 32 + lq * 8) ^ kx]; \
    } } while (0)

#define RD_B(d, qn, dst) do { _Pragma("unroll") for (int fj = 0; fj < 2; ++fj) { \
        const int rr = waveN + (qn) * 32 + fj * 16 + lr;                    \
        const int kx = ((rr >> 2) & 1) << 4;                                \
        _Pragma("unroll") for (int ks = 0; ks < 2; ++ks)                    \
            dst[fj][ks] = *(const bf16x8*)&LB[d][rr][(ks * 32 + lq * 8) ^ kx]; \
    } } while (0)

#define MM(qm, qn, bfx) do {                                                \
    __builtin_amdgcn_s_setprio(1);                                          \
    _Pragma("unroll") for (int ks = 0; ks < 2; ++ks)                        \
    _Pragma("unroll") for (int fi = 0; fi < 4; ++fi)                        \
    _Pragma("unroll") for (int fj = 0; fj < 2; ++fj)                        \
        acc[(qm) * 4 + fi][(qn) * 2 + fj] =                                 \
            __builtin_amdgcn_mfma_f32_16x16x32_bf16(                        \
                af[fi][ks], bfx[fj][ks],                                    \
                acc[(qm) * 4 + fi][(qn) * 2 + fj], 0, 0, 0);                \
    __builtin_amdgcn_s_setprio(0); } while (0)

#define ST_A(d, mh, kt) do { _Pragma("unroll") for (int c = 0; c < 2; ++c) { \
        const int ch = c * 512 + tid;                                       \
        const int rt = (mh) * 128 + (ch >> 3);                              \
        const int ke = ((ch & 7) * 8) ^ (((rt >> 2) & 1) << 4);             \
        GLOAD_LDS16(&encb[(size_t)(m0 + rt) * HIDDEN + (kt) * QBK + ke],    \
                    (char*)&LA[d][rt][0] + (ch & 7) * 16);                  \
    } } while (0)

#define ST_B(d, mh, kt) do { _Pragma("unroll") for (int c = 0; c < 2; ++c) { \
        const int ch = c * 512 + tid;                                       \
        const int rt = (mh) * 128 + (ch >> 3);                              \
        const int ke = ((ch & 7) * 8) ^ (((rt >> 2) & 1) << 4);             \
        GLOAD_LDS16(&Wb[(size_t)(n0 + rt) * HIDDEN + (kt) * QBK + ke],      \
                    (char*)&LB[d][rt][0] + (ch & 7) * 16);                  \
    } } while (0)

    f32x4  acc[8][4] = {};
    bf16x8 af[4][2], bf0[2][2], bf1[2][2];

    // prologue: d0 full (tile 0) + B d1 (tile 1); retire d0; publish.
    ST_A(0, 0, 0); ST_A(0, 1, 0); ST_B(0, 0, 0); ST_B(0, 1, 0);
    ST_B(1, 0, 1); ST_B(1, 1, 1);
    WAITV4(); SCHED0();                 // d0's 8 retired; B-d1 (4) in flight
    BARRIER();

    #pragma unroll 1
    for (int i = 0; i < NITER; ++i) {
        const bool st  = (i + 1 < NITER);
        const int kd1 = 2 * i + 1;     // this iter's d1 tile (A staged P1/P2)
        const int ka  = 2 * i + 2;     // next-iter d0 tile
        const int kb2 = 2 * i + 3;     // next-iter d1 tile

        // ---- P1: Q(0,0) of tile 2i (d0); stage A-d1 h0 (this iter's P5)
        RD_A(0, 0); RD_B(0, 0, bf0);
        ST_A(1, 0, kd1);
        BARRIER();
        MM(0, 0, bf0);
        BARRIER();
        // ---- P2: Q(0,1); stage A-d1 h1
        RD_B(0, 1, bf1);
        ST_A(1, 1, kd1);
        BARRIER();
        MM(0, 1, bf1);
        BARRIER();
        // ---- P3: Q(1,1); stage B-d0 h0 (next iter)  [B d0 reads done @P2]
        RD_A(0, 1);
        if (st) ST_B(0, 0, ka);
        BARRIER();
        MM(1, 1, bf1);
        BARRIER();
        // ---- P4: Q(1,0); stage B-d0 h1; counted wait (retire prev B-d1 +
        //          cur A-d1, keep cur B-d0 in flight)
        if (st) { ST_B(0, 1, ka); WAITV4(); } else { WAITV0(); }
        SCHED0();
        MM(1, 0, bf0);
        BARRIER();
        // ---- P5: Q(0,0) of tile 2i+1 (d1); stage A-d0 h0 [A d0 reads @P3]
        RD_A(1, 0); RD_B(1, 0, bf0);
        if (st) ST_A(0, 0, ka);
        BARRIER();
        MM(0, 0, bf0);
        BARRIER();
        // ---- P6: Q(0,1); stage A-d0 h1
        RD_B(1, 1, bf1);
        if (st) ST_A(0, 1, ka);
        BARRIER();
        MM(0, 1, bf1);
        BARRIER();
        // ---- P7: Q(1,1); stage B-d1 h0 (next iter)  [B d1 reads done @P6]
        RD_A(1, 1);
        if (st) ST_B(1, 0, kb2);
        BARRIER();
        MM(1, 1, bf1);
        BARRIER();
        // ---- P8: Q(1,0); stage B-d1 h1; counted wait (retire d0 stages,
        //          keep B-d1 pair in flight)
        if (st) { ST_B(1, 1, kb2); WAITV4(); }
        SCHED0();
        MM(1, 0, bf0);
        BARRIER();
    }

    // Epilogue. C/D: col = lane&15, row = (lane>>4)*4 + reg.
    const int b = m0 >> 11;                   // 256 | 2048 -> block-uniform
    const float* decb = dec + (size_t)b * HIDDEN;

    float2 dv[4];
    #pragma unroll
    for (int bj = 0; bj < 4; ++bj) {
        const int n = n0 + waveN + (bj >> 1) * 32 + (bj & 1) * 16 + lr;
        dv[bj] = make_float2(decb[n], v[n]);
    }

    const size_t plane = (size_t)(nt * 4 + (wid & 3)) * MTOT;

    #pragma unroll
    for (int ai = 0; ai < 8; ++ai) {
        const int rowoff = (ai >> 2) * 64 + (ai & 3) * 16;
        #pragma unroll
        for (int r = 0; r < 4; ++r) {
            const int m = m0 + waveM + rowoff + lq * 4 + r;
            float rp = 0.f;
            #pragma unroll
            for (int bj = 0; bj < 4; ++bj)
                rp = fmaf(fast_tanh(acc[ai][bj][r] + dv[bj].x), dv[bj].y, rp);
            rp += __shfl_xor(rp, 1, 64);
            rp += __shfl_xor(rp, 2, 64);
            rp += __shfl_xor(rp, 4, 64);
            rp += __shfl_xor(rp, 8, 64);
            if (lr == 0) outp[plane + m] = rp;
        }
    }
#undef RD_A
#undef RD_B
#undef MM
#undef ST_A
#undef ST_B
}

// ---------------------------------------------------------------------------
// softmax over SEQ per batch; PARTIALS sums 16 planes first.
// ---------------------------------------------------------------------------
template <bool PARTIALS>
__global__ __launch_bounds__(256) void softmax_k(
    const float* __restrict__ scores, float* __restrict__ wts)
{
    __shared__ float redmax[4];
    __shared__ float redsum[4];
    const int b = blockIdx.x;
    const int tid = threadIdx.x;

    float vals[8];
    float lmax = -1e30f;
    #pragma unroll
    for (int j = 0; j < 8; ++j) {
        const int idx = b * SEQ + tid + j * 256;
        float s;
        if (PARTIALS) {
            s = 0.f;
            #pragma unroll
            for (int p = 0; p < N_PLANES; ++p)
                s += scores[(size_t)p * MTOT + idx];
        } else {
            s = scores[idx];
        }
        vals[j] = s;
        lmax = fmaxf(lmax, s);
    }
    #pragma unroll
    for (int off = 1; off < 64; off <<= 1)
        lmax = fmaxf(lmax, __shfl_xor(lmax, off, 64));
    if ((tid & 63) == 0) redmax[tid >> 6] = lmax;
    __syncthreads();
    const float gmax = fmaxf(fmaxf(redmax[0], redmax[1]),
                             fmaxf(redmax[2], redmax[3]));

    float lsum = 0.f;
    #pragma unroll
    for (int j = 0; j < 8; ++j) {
        vals[j] = expf(vals[j] - gmax);
        lsum += vals[j];
    }
    #pragma unroll
    for (int off = 1; off < 64; off <<= 1)
        lsum += __shfl_xor(lsum, off, 64);
    if ((tid & 63) == 0) redsum[tid >> 6] = lsum;
    __syncthreads();
    const float inv = 1.f / (redsum[0] + redsum[1] + redsum[2] + redsum[3]);

    #pragma unroll
    for (int j = 0; j < 8; ++j)
        wts[b * SEQ + tid + j * 256] = vals[j] * inv;
}

// ---------------------------------------------------------------------------
// context[b,h] = sum_s w[b,s] * enc[b,s,h], bf16 enc copy (rounds 2-7).
// ---------------------------------------------------------------------------
__global__ __launch_bounds__(256) void context_bf16_k(
    const unsigned short* __restrict__ encb,
    const float* __restrict__ w,
    float* __restrict__ ctx)
{
    const int b     = blockIdx.x >> 3;
    const int chunk = blockIdx.x & 7;
    const int sOff  = threadIdx.x >> 4;
    const int hg    = threadIdx.x & 15;
    const int h     = chunk * 128 + hg * 8;

    float acc[8] = {};
    for (int s = sOff; s < SEQ; s += 16) {
        const float ws = w[b * SEQ + s];
        ushort8 e = *(const ushort8*)&encb[(size_t)(b * SEQ + s) * HIDDEN + h];
        #pragma unroll
        for (int j = 0; j < 8; ++j)
            acc[j] = fmaf(ws, __uint_as_float((unsigned)e[j] << 16), acc[j]);
    }
    __shared__ float red[16][128];
    #pragma unroll
    for (int j = 0; j < 8; ++j) red[sOff][hg * 8 + j] = acc[j];
    __syncthreads();
    if (threadIdx.x < 128) {
        float r = 0.f;
        #pragma unroll
        for (int g = 0; g < 16; ++g) r += red[g][threadIdx.x];
        ctx[b * HIDDEN + chunk * 128 + threadIdx.x] = r;
    }
}

// ---------------------------------------------------------------------------
// Fallback fp32 path (tiny workspace only).
// ---------------------------------------------------------------------------
__global__ __launch_bounds__(256) void score_gemm_f32(
    const float* __restrict__ enc, const float* __restrict__ W,
    const float* __restrict__ dec, const float* __restrict__ v,
    float* __restrict__ scores)
{
    __shared__ float As[16][64 + 1];
    __shared__ float Bs[16][64 + 1];
    const int tid = threadIdx.x;
    const int m0 = (blockIdx.x >> 4) * 64;
    const int n0 = (blockIdx.x & 15) * 64;
    const int ty = tid >> 4, tx = tid & 15;
    const int lr = tid >> 2, lc = tid & 3;
    float acc[4][4] = {};
    for (int k0 = 0; k0 < HIDDEN; k0 += 16) {
        float4 a = *(const float4*)&enc[(size_t)(m0 + lr) * HIDDEN + k0 + lc * 4];
        float4 b = *(const float4*)&W  [(size_t)(n0 + lr) * HIDDEN + k0 + lc * 4];
        __syncthreads();
        As[lc*4+0][lr]=a.x; As[lc*4+1][lr]=a.y; As[lc*4+2][lr]=a.z; As[lc*4+3][lr]=a.w;
        Bs[lc*4+0][lr]=b.x; Bs[lc*4+1][lr]=b.y; Bs[lc*4+2][lr]=b.z; Bs[lc*4+3][lr]=b.w;
        __syncthreads();
        #pragma unroll
        for (int k = 0; k < 16; ++k) {
            float4 av = *(const float4*)&As[k][ty * 4];
            float4 bv = *(const float4*)&Bs[k][tx * 4];
            float aa[4] = {av.x, av.y, av.z, av.w};
            float bb[4] = {bv.x, bv.y, bv.z, bv.w};
            #pragma unroll
            for (int i = 0; i < 4; ++i)
                #pragma unroll
                for (int j = 0; j < 4; ++j)
                    acc[i][j] = fmaf(aa[i], bb[j], acc[i][j]);
        }
    }
    float rowpart[4];
    #pragma unroll
    for (int i = 0; i < 4; ++i) {
        const int m = m0 + ty * 4 + i;
        const int b = m >> 11;
        float rp = 0.f;
        #pragma unroll
        for (int j = 0; j < 4; ++j) {
            const int n = n0 + tx * 4 + j;
            rp = fmaf(fast_tanh(acc[i][j] + dec[b * HIDDEN + n]), v[n], rp);
        }
        rowpart[i] = rp;
    }
    #pragma unroll
    for (int off = 1; off <= 8; off <<= 1)
        #pragma unroll
        for (int i = 0; i < 4; ++i)
            rowpart[i] += __shfl_xor(rowpart[i], off, 64);
    if (tx == 0)
        #pragma unroll
        for (int i = 0; i < 4; ++i)
            atomicAdd(&scores[m0 + ty * 4 + i], rowpart[i]);
}

__global__ __launch_bounds__(256) void context_f32_k(
    const float* __restrict__ enc,
    const float* __restrict__ w,
    float* __restrict__ ctx)
{
    const int b     = blockIdx.x >> 3;
    const int chunk = blockIdx.x & 7;
    const int sOff  = threadIdx.x >> 5;
    const int quad  = threadIdx.x & 31;
    const int h     = chunk * 128 + quad * 4;

    float4 acc = {0.f, 0.f, 0.f, 0.f};
    #pragma unroll 4
    for (int s = sOff; s < SEQ; s += 8) {
        const float ws = w[b * SEQ + s];
        const float4 e = *(const float4*)&enc[(size_t)(b * SEQ + s) * HIDDEN + h];
        acc.x = fmaf(ws, e.x, acc.x);
        acc.y = fmaf(ws, e.y, acc.y);
        acc.z = fmaf(ws, e.z, acc.z);
        acc.w = fmaf(ws, e.w, acc.w);
    }
    __shared__ float4 red[8][32];
    red[sOff][quad] = acc;
    __syncthreads();
    if (sOff == 0) {
        float4 r = red[0][quad];
        #pragma unroll
        for (int t = 1; t < 8; ++t) {
            r.x += red[t][quad].x; r.y += red[t][quad].y;
            r.z += red[t][quad].z; r.w += red[t][quad].w;
        }
        *(float4*)&ctx[b * HIDDEN + h] = r;
    }
}

// ---------------------------------------------------------------------------
extern "C" void kernel_launch(void* const* d_in, const int* in_sizes, int n_in,
                              void* d_out, int out_size, void* d_ws, size_t ws_size,
                              hipStream_t stream) {
    const float* dec = (const float*)d_in[0];   // [32, 1024]
    const float* enc = (const float*)d_in[1];   // [32, 2048, 1024]
    const float* W   = (const float*)d_in[2];   // [1024, 1024]
    const float* v   = (const float*)d_in[3];   // [1, 1024]

    float* out = (float*)d_out;
    float* ctx = out;                           // [32, 1024]
    float* wts = out + BATCH * HIDDEN;          // [32, 2048]

    const size_t part_bytes   = (size_t)N_PLANES * MTOT * sizeof(float); // 4 MiB
    const size_t wb_bytes     = (size_t)HIDDEN * HIDDEN * 2;             // 2 MiB
    const size_t encb_bytes   = (size_t)MTOT * HIDDEN * 2;               // 128 MiB
    const size_t scores_bytes = (size_t)MTOT * sizeof(float);            // 256 KiB
    const size_t need = part_bytes + wb_bytes + encb_bytes;              // 134 MiB

    if (ws_size >= need) {
        float* partial       = (float*)d_ws;
        unsigned short* Wb   = (unsigned short*)((char*)d_ws + part_bytes);
        unsigned short* encb = (unsigned short*)((char*)d_ws + part_bytes + wb_bytes);

        convert_k<<<dim3(2048), dim3(256), 0, stream>>>(enc, encb, W, Wb);
        gemm8p<<<dim3(1024), dim3(512), 0, stream>>>(encb, Wb, dec, v, partial);
        softmax_k<true><<<dim3(BATCH), dim3(256), 0, stream>>>(partial, wts);
        context_bf16_k<<<dim3(BATCH * 8), dim3(256), 0, stream>>>(encb, wts, ctx);
    } else {
        float* scores = (float*)d_ws;
        (void)hipMemsetAsync(scores, 0, scores_bytes, stream);
        score_gemm_f32<<<dim3(16384), dim3(256), 0, stream>>>(enc, W, dec, v, scores);
        softmax_k<false><<<dim3(BATCH), dim3(256), 0, stream>>>(scores, wts);
        context_f32_k<<<dim3(BATCH * 8), dim3(256), 0, stream>>>(enc, wts, ctx);
    }
}

// Round 16
// 208.075 us; speedup vs baseline: 1.6255x; 1.2896x over previous
//
#include <hip/hip_runtime.h>
#include <hip/hip_bf16.h>
#include <math.h>

#define HIDDEN 1024
#define BATCH 32
#define SEQ 2048
#define MTOT (BATCH * SEQ)   // 65536 rows
#define N_PLANES 8           // 4 n-tiles x 2 wn-waves

#define BM 128
#define BN 256
#define BK 32
#define NKS (HIDDEN / BK)    // 32 K-steps

typedef __attribute__((ext_vector_type(8))) short          bf16x8;
typedef __attribute__((ext_vector_type(8))) unsigned short ushort8;
typedef __attribute__((ext_vector_type(4))) float          f32x4;

#define GLOAD_LDS16(g, l) __builtin_amdgcn_global_load_lds( \
    (const __attribute__((address_space(1))) void*)(g),      \
    (__attribute__((address_space(3))) void*)(l), 16, 0, 0)

#define BARRIER() asm volatile("s_barrier" ::: "memory")
#define WAITL0()  asm volatile("s_waitcnt lgkmcnt(0)" ::: "memory")
#define WAITL6()  asm volatile("s_waitcnt lgkmcnt(6)" ::: "memory")
#define WAITV4()  asm volatile("s_waitcnt vmcnt(4)" ::: "memory")
#define WAITV8()  asm volatile("s_waitcnt vmcnt(8)" ::: "memory")
#define WAITV0()  asm volatile("s_waitcnt vmcnt(0)" ::: "memory")
#define SCHED0()  __builtin_amdgcn_sched_barrier(0)

// tanh(x) = 1 - 2/(exp2(x*2*log2e)+1); saturates exactly via exp2 inf/0.
__device__ __forceinline__ float fast_tanh(float x) {
    float e = __builtin_amdgcn_exp2f(x * 2.8853900817779268f);
    return 1.0f - 2.0f * __builtin_amdgcn_rcpf(1.0f + e);
}

// 8x fp32 -> bf16 RNE (bit-trick, same numerics as the convert kernels)
__device__ __forceinline__ ushort8 cvt8(float4 lo, float4 hi) {
    float va[8] = {lo.x, lo.y, lo.z, lo.w, hi.x, hi.y, hi.z, hi.w};
    ushort8 r;
    #pragma unroll
    for (int j = 0; j < 8; ++j) {
        unsigned u = __float_as_uint(va[j]);
        r[j] = (unsigned short)((u + 0x7FFFu + ((u >> 16) & 1u)) >> 16);
    }
    return r;
}

// ---------------------------------------------------------------------------
// fp32 -> bf16 (RNE) conversion for W ONLY (4 MB).
// ---------------------------------------------------------------------------
__global__ __launch_bounds__(256) void convert_w_k(
    const float* __restrict__ W, unsigned short* __restrict__ Wb)
{
    const int i = blockIdx.x * blockDim.x + threadIdx.x;   // 131072 chunks
    float4 a = ((const float4*)W)[(size_t)i * 2];
    float4 b = ((const float4*)W)[(size_t)i * 2 + 1];
    *(ushort8*)&Wb[(size_t)i * 8] = cvt8(a, b);
}

// ---------------------------------------------------------------------------
// MFMA score GEMM, BM=128 x BN=256, BK=32, 4 waves, 3-buffer rotation,
// fused A-conversion (1-step-deferred write), SINGLE BARRIER PER K-STEP.
// (Round-10 structure — measured session optimum. Rounds 11-15 tested
// A-direct-load, encb side-write fusion, and the 256^2 8-phase template;
// all regressed for this shape: M=65536, K=1024-thin, reduce-epilogue.)
//
// Hazard audit (why 1 barrier suffices):
//  - Within step t: reads touch only buf cur=t%3; writeA targets (t+1)%3;
//    stageB/loadA target (t+2)%3 — disjoint by rotation.
//  - As[(t+1)%3] write (step t) vs its prior readers (step t-2, as cur):
//    reader's own WAITL* (pre-MFMA, step t-2) + end-of-(t-2),(t-1) barriers.
//  - Bs[(t+2)%3] re-stage (step t) vs prior readers (step t-1): reader's own
//    WAITL0 (step t-1) + end-of-(t-1) barrier.
//  - Publication of As[t+1]/Bs[t+1] for step t+1: writer's ds_writes drain
//    at its lgkmcnt(0) (pre-MFMA2); B staging retired by WAITV8; then the
//    single end-of-step barrier publishes both.
// vmcnt ledger (issue order pinned by SCHED0):
//  entering t: [A(t+1)x8, B(t+1)x4]. WAITV4 -> A(t+1) done -> writeA.
//  issue A(t+2)x8 + B(t+2)x4. WAITV8 (post-MFMA) -> B(t+1) resident,
//  leaves A/B(t+2) in flight. Tails: t=30 WAITV0; t=31 none.
// lgkm split: WAITL6 -> first 8 ds_reads ready -> MFMA cluster 1 overlaps
// bf4-7 + writes draining; WAITL0 -> MFMA cluster 2.
// PARTIALS=true : wave-private planes partial[(nt*2+(wid&1))*MTOT + m].
// ---------------------------------------------------------------------------
template <bool PARTIALS>
__global__ __launch_bounds__(256, 2) void score_gemm_mfma(
    const float* __restrict__ enc,            // [MTOT][HIDDEN] fp32
    const unsigned short* __restrict__ Wb,    // [HIDDEN][HIDDEN] bf16 (out,in)
    const float* __restrict__ dec,            // [BATCH][HIDDEN]
    const float* __restrict__ v,              // [HIDDEN]
    float* __restrict__ outp)                 // partial[8][MTOT] or scores[MTOT]
{
    __shared__ unsigned short As[3][BM][BK];   // 24 KiB
    __shared__ unsigned short Bs[3][BN][BK];   // 48 KiB

    // XCD-grouping swizzle (bijective: 2048 blocks = 8 xcds x 256 slots)
    const int bid  = blockIdx.x;
    const int xcd  = bid & 7;
    const int slot = bid >> 3;                 // 0..255
    const int mt   = xcd * 64 + (slot >> 2);   // 0..511
    const int nt   = slot & 3;                 // 0..3
    const int m0   = mt * BM;
    const int n0   = nt * BN;

    const int tid  = threadIdx.x;
    const int wid  = tid >> 6;
    const int lane = tid & 63;
    const int wm   = (wid >> 1) * 64;          // 0 / 64
    const int wn   = (wid & 1) * 128;          // 0 / 128

    // LDS read address (16B slot q = lane>>4 within the 64B k-row)
    const int rowb = (lane & 15) * 64;
    const int swzb = (((lane >> 4) ^ (lane & 3)) * 16);

    // A chunks (2 per thread); global k pre-swizzled to keep LDS linear
    const int chA0  = wid * 64 + lane;
    const int chA1  = 256 + wid * 64 + lane;
    const int rowA0 = chA0 >> 2, rowA1 = chA1 >> 2;
    const float* encA0 = &enc[(size_t)(m0 + rowA0) * HIDDEN
                              + (((chA0 & 3) ^ (rowA0 & 3)) * 8)];
    const float* encA1 = &enc[(size_t)(m0 + rowA1) * HIDDEN
                              + (((chA1 & 3) ^ (rowA1 & 3)) * 8)];

    auto loadA = [&](int k0, float4& l0, float4& h0, float4& l1, float4& h1) {
        l0 = *(const float4*)(encA0 + k0);
        h0 = *(const float4*)(encA0 + k0 + 4);
        l1 = *(const float4*)(encA1 + k0);
        h1 = *(const float4*)(encA1 + k0 + 4);
    };
    auto writeA = [&](int buf, float4 l0, float4 h0, float4 l1, float4 h1) {
        *(ushort8*)((char*)&As[buf][0][0] + (size_t)chA0 * 16) = cvt8(l0, h0);
        *(ushort8*)((char*)&As[buf][0][0] + (size_t)chA1 * 16) = cvt8(l1, h1);
    };
    auto stageB = [&](int buf, int k0) {
        #pragma unroll
        for (int c = 0; c < 4; ++c) {
            const int chw = c * 256 + wid * 64;
            const int ch  = chw + lane;
            const int row = ch >> 2;
            const int gk  = k0 + (((ch & 3) ^ (row & 3)) * 8);
            GLOAD_LDS16(&Wb[(size_t)(n0 + row) * HIDDEN + gk],
                        (char*)&Bs[buf][0][0] + (size_t)chw * 16);
        }
    };

    // prologue: write As[0], As[1]; stage B(0), B(1); leave B(1)x4 in flight.
    {
        float4 p0l0, p0h0, p0l1, p0h1, p1l0, p1h0, p1l1, p1h1;
        loadA(0, p0l0, p0h0, p0l1, p0h1);
        stageB(0, 0);
        loadA(BK, p1l0, p1h0, p1l1, p1h1);
        stageB(1, BK);
        asm volatile("s_waitcnt vmcnt(12)" ::: "memory"); SCHED0(); // A(0) done
        writeA(0, p0l0, p0h0, p0l1, p0h1);
        WAITV4(); SCHED0();                              // A(1)+B(0) done
        writeA(1, p1l0, p1h0, p1l1, p1h1);
        WAITL0(); SCHED0();
        BARRIER();
    }

    f32x4 acc[4][8] = {};
    float4 al0, ah0, al1, ah1;   // A(t+2) fp32 in flight (one set)

    #pragma unroll 1
    for (int t = 0; t < NKS; ++t) {
        const int cur  = t % 3;
        const int nxt  = (t + 2) % 3;
        const int prv  = (t + 1) % 3;           // buffer receiving A(t+1)
        const bool more = (t + 2 < NKS);
        const int knxt = (t + 2) * BK;
        const char* Ab = (const char*)&As[cur][0][0];
        const char* Bb = (const char*)&Bs[cur][0][0];

        bf16x8 af[4], bf[8];

        // issue all 12 ds_reads of buf cur (af0-3, bf0-3, bf4-7 in order)
        #pragma unroll
        for (int fi = 0; fi < 4; ++fi)
            af[fi] = *(const bf16x8*)(Ab + (wm + fi * 16) * 64 + rowb + swzb);
        #pragma unroll
        for (int fj = 0; fj < 8; ++fj)
            bf[fj] = *(const bf16x8*)(Bb + (wn + fj * 16) * 64 + rowb + swzb);
        SCHED0();

        // retire A(t+1) fp32 loads; convert + ds_write into As[prv]
        if (t >= 1 && t + 1 < NKS) {
            WAITV4(); SCHED0();
            writeA(prv, al0, ah0, al1, ah1);
            SCHED0();
        }
        // issue next prefetch (A then B — ledger order)
        if (more) {
            loadA(knxt, al0, ah0, al1, ah1);
            SCHED0();
            stageB(nxt, knxt);
            SCHED0();
        }

        // MFMA cluster 1: needs af0-3 + bf0-3 (first 8 ds_reads)
        WAITL6(); SCHED0();
        __builtin_amdgcn_s_setprio(1);
        #pragma unroll
        for (int fi = 0; fi < 4; ++fi)
            #pragma unroll
            for (int fj = 0; fj < 4; ++fj)
                acc[fi][fj] = __builtin_amdgcn_mfma_f32_16x16x32_bf16(
                    af[fi], bf[fj], acc[fi][fj], 0, 0, 0);
        __builtin_amdgcn_s_setprio(0);
        SCHED0();

        // MFMA cluster 2: needs bf4-7 (drains everything incl. writeA)
        WAITL0(); SCHED0();
        __builtin_amdgcn_s_setprio(1);
        #pragma unroll
        for (int fi = 0; fi < 4; ++fi)
            #pragma unroll
            for (int fj = 4; fj < 8; ++fj)
                acc[fi][fj] = __builtin_amdgcn_mfma_f32_16x16x32_bf16(
                    af[fi], bf[fj], acc[fi][fj], 0, 0, 0);
        __builtin_amdgcn_s_setprio(0);
        SCHED0();

        // retire B(t+1) (leave A/B(t+2) in flight); publish; next step
        if (more)             { WAITV8(); }
        else if (t + 1 < NKS) { WAITV0(); }     // t=30: drain B(31)
        SCHED0();
        if (t + 1 < NKS) BARRIER();
    }

    // Epilogue. C/D layout: col = lane&15, row = (lane>>4)*4 + reg.
    const int rowgrp = lane >> 4;
    const int col    = lane & 15;
    const int b      = m0 >> 11;               // batch (block-uniform)
    const float* decb = dec + (size_t)b * HIDDEN;

    float2 dv[8];
    #pragma unroll
    for (int fj = 0; fj < 8; ++fj) {
        const int n = n0 + wn + fj * 16 + col;
        dv[fj] = make_float2(decb[n], v[n]);
    }

    const size_t plane = (size_t)(nt * 2 + (wid & 1)) * MTOT;  // wave-private

    #pragma unroll
    for (int fi = 0; fi < 4; ++fi) {
        #pragma unroll
        for (int r = 0; r < 4; ++r) {
            const int m = m0 + wm + fi * 16 + rowgrp * 4 + r;
            float rp = 0.f;
            #pragma unroll
            for (int fj = 0; fj < 8; ++fj)
                rp = fmaf(fast_tanh(acc[fi][fj][r] + dv[fj].x), dv[fj].y, rp);
            rp += __shfl_xor(rp, 1, 64);
            rp += __shfl_xor(rp, 2, 64);
            rp += __shfl_xor(rp, 4, 64);
            rp += __shfl_xor(rp, 8, 64);
            if (col == 0) {
                if (PARTIALS) outp[plane + m] = rp;
                else          atomicAdd(&outp[m], rp);
            }
        }
    }
}

// ---------------------------------------------------------------------------
// softmax over SEQ per batch. PARTIALS: sum 8 partial score planes first.
// ---------------------------------------------------------------------------
template <bool PARTIALS>
__global__ __launch_bounds__(256) void softmax_k(
    const float* __restrict__ scores, float* __restrict__ wts)
{
    __shared__ float redmax[4];
    __shared__ float redsum[4];
    const int b = blockIdx.x;
    const int tid = threadIdx.x;

    float vals[8];
    float lmax = -1e30f;
    #pragma unroll
    for (int j = 0; j < 8; ++j) {
        const int idx = b * SEQ + tid + j * 256;
        float s;
        if (PARTIALS) {
            s = 0.f;
            #pragma unroll
            for (int p = 0; p < N_PLANES; ++p)
                s += scores[(size_t)p * MTOT + idx];
        } else {
            s = scores[idx];
        }
        vals[j] = s;
        lmax = fmaxf(lmax, s);
    }
    #pragma unroll
    for (int off = 1; off < 64; off <<= 1)
        lmax = fmaxf(lmax, __shfl_xor(lmax, off, 64));
    if ((tid & 63) == 0) redmax[tid >> 6] = lmax;
    __syncthreads();
    const float gmax = fmaxf(fmaxf(redmax[0], redmax[1]),
                             fmaxf(redmax[2], redmax[3]));

    float lsum = 0.f;
    #pragma unroll
    for (int j = 0; j < 8; ++j) {
        vals[j] = expf(vals[j] - gmax);
        lsum += vals[j];
    }
    #pragma unroll
    for (int off = 1; off < 64; off <<= 1)
        lsum += __shfl_xor(lsum, off, 64);
    if ((tid & 63) == 0) redsum[tid >> 6] = lsum;
    __syncthreads();
    const float inv = 1.f / (redsum[0] + redsum[1] + redsum[2] + redsum[3]);

    #pragma unroll
    for (int j = 0; j < 8; ++j)
        wts[b * SEQ + tid + j * 256] = vals[j] * inv;
}

// ---------------------------------------------------------------------------
// context[b,h] = sum_s w[b,s] * enc[b,s,h], fp32 enc, float4 loads.
// ---------------------------------------------------------------------------
__global__ __launch_bounds__(256) void context_f32_k(
    const float* __restrict__ enc,
    const float* __restrict__ w,
    float* __restrict__ ctx)
{
    const int b     = blockIdx.x >> 3;
    const int chunk = blockIdx.x & 7;
    const int sOff  = threadIdx.x >> 5;        // 0..7
    const int quad  = threadIdx.x & 31;        // 0..31
    const int h     = chunk * 128 + quad * 4;

    float4 acc = {0.f, 0.f, 0.f, 0.f};
    #pragma unroll 4
    for (int s = sOff; s < SEQ; s += 8) {
        const float ws = w[b * SEQ + s];
        const float4 e = *(const float4*)&enc[(size_t)(b * SEQ + s) * HIDDEN + h];
        acc.x = fmaf(ws, e.x, acc.x);
        acc.y = fmaf(ws, e.y, acc.y);
        acc.z = fmaf(ws, e.z, acc.z);
        acc.w = fmaf(ws, e.w, acc.w);
    }

    __shared__ float4 red[8][32];
    red[sOff][quad] = acc;
    __syncthreads();
    if (sOff == 0) {
        float4 r = red[0][quad];
        #pragma unroll
        for (int t = 1; t < 8; ++t) {
            r.x += red[t][quad].x; r.y += red[t][quad].y;
            r.z += red[t][quad].z; r.w += red[t][quad].w;
        }
        *(float4*)&ctx[b * HIDDEN + h] = r;
    }
}

// ---------------------------------------------------------------------------
// Fallback fp32 path (no workspace beyond scores).
// ---------------------------------------------------------------------------
__global__ __launch_bounds__(256) void score_gemm_f32(
    const float* __restrict__ enc, const float* __restrict__ W,
    const float* __restrict__ dec, const float* __restrict__ v,
    float* __restrict__ scores)
{
    __shared__ float As[16][64 + 1];
    __shared__ float Bs[16][64 + 1];
    const int tid = threadIdx.x;
    const int m0 = (blockIdx.x >> 4) * 64;
    const int n0 = (blockIdx.x & 15) * 64;
    const int ty = tid >> 4, tx = tid & 15;
    const int lr = tid >> 2, lc = tid & 3;
    float acc[4][4] = {};
    for (int k0 = 0; k0 < HIDDEN; k0 += 16) {
        float4 a = *(const float4*)&enc[(size_t)(m0 + lr) * HIDDEN + k0 + lc * 4];
        float4 b = *(const float4*)&W  [(size_t)(n0 + lr) * HIDDEN + k0 + lc * 4];
        __syncthreads();
        As[lc*4+0][lr]=a.x; As[lc*4+1][lr]=a.y; As[lc*4+2][lr]=a.z; As[lc*4+3][lr]=a.w;
        Bs[lc*4+0][lr]=b.x; Bs[lc*4+1][lr]=b.y; Bs[lc*4+2][lr]=b.z; Bs[lc*4+3][lr]=b.w;
        __syncthreads();
        #pragma unroll
        for (int k = 0; k < 16; ++k) {
            float4 av = *(const float4*)&As[k][ty * 4];
            float4 bv = *(const float4*)&Bs[k][tx * 4];
            float aa[4] = {av.x, av.y, av.z, av.w};
            float bb[4] = {bv.x, bv.y, bv.z, bv.w};
            #pragma unroll
            for (int i = 0; i < 4; ++i)
                #pragma unroll
                for (int j = 0; j < 4; ++j)
                    acc[i][j] = fmaf(aa[i], bb[j], acc[i][j]);
        }
    }
    float rowpart[4];
    #pragma unroll
    for (int i = 0; i < 4; ++i) {
        const int m = m0 + ty * 4 + i;
        const int b = m >> 11;
        float rp = 0.f;
        #pragma unroll
        for (int j = 0; j < 4; ++j) {
            const int n = n0 + tx * 4 + j;
            rp = fmaf(fast_tanh(acc[i][j] + dec[b * HIDDEN + n]), v[n], rp);
        }
        rowpart[i] = rp;
    }
    #pragma unroll
    for (int off = 1; off <= 8; off <<= 1)
        #pragma unroll
        for (int i = 0; i < 4; ++i)
            rowpart[i] += __shfl_xor(rowpart[i], off, 64);
    if (tx == 0)
        #pragma unroll
        for (int i = 0; i < 4; ++i)
            atomicAdd(&scores[m0 + ty * 4 + i], rowpart[i]);
}

// ---------------------------------------------------------------------------
extern "C" void kernel_launch(void* const* d_in, const int* in_sizes, int n_in,
                              void* d_out, int out_size, void* d_ws, size_t ws_size,
                              hipStream_t stream) {
    const float* dec = (const float*)d_in[0];   // [32, 1024]
    const float* enc = (const float*)d_in[1];   // [32, 2048, 1024]
    const float* W   = (const float*)d_in[2];   // [1024, 1024]
    const float* v   = (const float*)d_in[3];   // [1, 1024]

    float* out = (float*)d_out;
    float* ctx = out;                           // [32, 1024]
    float* wts = out + BATCH * HIDDEN;          // [32, 2048]

    const size_t part_bytes   = (size_t)N_PLANES * MTOT * sizeof(float); // 2 MiB
    const size_t wb_bytes     = (size_t)HIDDEN * HIDDEN * 2;             // 2 MiB
    const size_t scores_bytes = (size_t)MTOT * sizeof(float);            // 256 KiB
    const size_t need = part_bytes + wb_bytes;                           // 4 MiB

    if (ws_size >= need) {
        float* partial       = (float*)d_ws;
        unsigned short* Wb   = (unsigned short*)((char*)d_ws + part_bytes);

        convert_w_k<<<dim3(512), dim3(256), 0, stream>>>(W, Wb);
        score_gemm_mfma<true><<<dim3(2048), dim3(256), 0, stream>>>(enc, Wb, dec, v, partial);
        softmax_k<true><<<dim3(BATCH), dim3(256), 0, stream>>>(partial, wts);
        context_f32_k<<<dim3(BATCH * 8), dim3(256), 0, stream>>>(enc, wts, ctx);
    } else {
        float* scores = (float*)d_ws;
        (void)hipMemsetAsync(scores, 0, scores_bytes, stream);
        score_gemm_f32<<<dim3(16384), dim3(256), 0, stream>>>(enc, W, dec, v, scores);
        softmax_k<false><<<dim3(BATCH), dim3(256), 0, stream>>>(scores, wts);
        context_f32_k<<<dim3(BATCH * 8), dim3(256), 0, stream>>>(enc, wts, ctx);
    }
}